// Round 10
// baseline (45.010 us; speedup 1.0000x reference)
//
#include <hip/hip_runtime.h>

// StructNConv2D_d_with_s — fused spatial (3x3) + channel (16x16) normalized conv.
// d,cd: (4,16,256,256) f32; s_prod_roll: (4,16,9,256,256) f32;
// spatial_weight: (16,1,9,1,1); channel_weight: (16,16,1,1).
// Outputs concatenated: d_out then cd_out, each (4,16,256,256) f32.
//
// R10 = R9 with the compile fix: __builtin_nontemporal_* requires a native
// clang vector type, not HIP_vector_type<float,4>. nt-load the zero-reuse
// s_prod_roll stream, nt-store the never-re-read outputs; keep L2 for the
// d/cd stencil rows. Structure = R6 best (38.0us): 2 c-split waves/block,
// reg accumulators an/ad[16]f4, half-exchange via 32KB LDS.

#define NB 4
#define NC 16
#define NH 256
#define NW 256
#define NK 9
#define HW (NH * NW)
#define TPB 128

static constexpr float kEPS = 1e-20f;

typedef float vf4 __attribute__((ext_vector_type(4)));   // native vector for nt builtins

__device__ __forceinline__ float frcp(float x) { return __builtin_amdgcn_rcpf(x); }

__global__ __launch_bounds__(TPB) void structnconv_fused(
    const float* __restrict__ g_d,
    const float* __restrict__ g_cd,
    const float* __restrict__ g_sp,   // s_prod_roll
    const float* __restrict__ g_sw,   // spatial_weight (16*9)
    const float* __restrict__ g_cw,   // channel_weight (16*16)
    float* __restrict__ g_dout,
    float* __restrict__ g_cdout)
{
    __shared__ float lds_sw[NC * NK];        // 576 B
    __shared__ float lds_cw[NC * NC];        // 1 KB
    __shared__ float lds_part[4];
    __shared__ float lds_x[2][8][2][NW];     // [writer][o_loc][an/ad][px] 32 KB

    const int t  = threadIdx.x;
    const int wv = t >> 6;        // wave id: 0 -> c 0..7, 1 -> c 8..15
    const int ln = t & 63;

    // ---- Stage weights + global sums (128 threads, 1 barrier) ----
    float s1 = g_sw[t];                       // t < 128 < 144
    float s2 = g_cw[t] + g_cw[TPB + t];
    lds_sw[t] = s1;
    lds_cw[t] = g_cw[t];
    lds_cw[TPB + t] = g_cw[TPB + t];
    if (t < NC * NK - TPB) {                  // 16 tail elements of sw
        const float v = g_sw[TPB + t];
        lds_sw[TPB + t] = v;
        s1 += v;
    }
    #pragma unroll
    for (int off = 32; off > 0; off >>= 1) {
        s1 += __shfl_down(s1, off);
        s2 += __shfl_down(s2, off);
    }
    if (ln == 0) {
        lds_part[wv]     = s1;
        lds_part[2 + wv] = s2;
    }
    __syncthreads();
    const float inv_sw_sum = frcp(lds_part[0] + lds_part[1] + kEPS);
    const float inv_cw_sum = frcp(lds_part[2] + lds_part[3] + kEPS);

    // ---- Block -> one (b,h) row (bijective XCD swizzle); thread -> 4 px ----
    const int bid = (int)blockIdx.x;                 // 0..1023
    const int swz = (bid & 7) * 128 + (bid >> 3);    // XCD n -> contiguous band
    const int b = swz >> 8;
    const int h = swz & (NH - 1);
    const int w0 = ln << 2;
    const int pix = h * NW + w0;

    // ---- Phase 1: spatial conv for this wave's 8 channels; accumulate
    //      channel-mix partials for ALL 16 output channels in registers ----
    float4 an[NC], ad[NC];
    #pragma unroll
    for (int o = 0; o < NC; ++o) {
        an[o] = make_float4(0.f, 0.f, 0.f, 0.f);
        ad[o] = make_float4(0.f, 0.f, 0.f, 0.f);
    }

    #pragma unroll 1
    for (int ci = 0; ci < 8; ++ci) {
        const int c = (wv << 3) + ci;     // wave-uniform
        const float* pdd = g_d  + (size_t)(b * NC + c) * HW + pix;
        const float* pcc = g_cd + (size_t)(b * NC + c) * HW + pix;
        const float* pss = g_sp + ((size_t)(b * NC + c) * NK) * HW + pix;

        // Stencil rows -> registers (static indices after unroll).
        float dr[3][6], cr[3][6];
        #pragma unroll
        for (int r = 0; r < 3; ++r) {
            const int hh = h + r - 1;
            const int roff = (r - 1) * NW;
            if ((unsigned)hh < (unsigned)NH) {
                const float4 md = *(const float4*)(pdd + roff);
                const float4 mc = *(const float4*)(pcc + roff);
                dr[r][1] = md.x; dr[r][2] = md.y; dr[r][3] = md.z; dr[r][4] = md.w;
                cr[r][1] = mc.x; cr[r][2] = mc.y; cr[r][3] = mc.z; cr[r][4] = mc.w;
                dr[r][0] = (w0 > 0)      ? pdd[roff - 1] : 0.f;
                cr[r][0] = (w0 > 0)      ? pcc[roff - 1] : 0.f;
                dr[r][5] = (w0 + 4 < NW) ? pdd[roff + 4] : 0.f;
                cr[r][5] = (w0 + 4 < NW) ? pcc[roff + 4] : 0.f;
            } else {
                #pragma unroll
                for (int j = 0; j < 6; ++j) { dr[r][j] = 0.f; cr[r][j] = 0.f; }
            }
        }

        // s_prod_roll: zero-reuse stream -> non-temporal (don't pollute L2).
        vf4 sp[NK];
        #pragma unroll
        for (int k = 0; k < NK; ++k)
            sp[k] = __builtin_nontemporal_load((const vf4*)(pss + (size_t)k * HW));

        float nom[4] = {0.f, 0.f, 0.f, 0.f};
        float den[4] = {0.f, 0.f, 0.f, 0.f};
        #pragma unroll
        for (int r = 0; r < 3; ++r) {
            #pragma unroll
            for (int dj = 0; dj < 3; ++dj) {
                const int k = r * 3 + dj;
                const float wck = lds_sw[c * NK + k];   // uniform -> broadcast
                const float sv[4] = {sp[k][0], sp[k][1], sp[k][2], sp[k][3]};
                #pragma unroll
                for (int p = 0; p < 4; ++p) {
                    const float cdp = cr[r][dj + p] * sv[p];
                    nom[p] = fmaf(cdp * dr[r][dj + p], wck, nom[p]);
                    den[p] = fmaf(cdp, wck, den[p]);
                }
            }
        }

        float4 csv, pdv;
        csv.x = den[0] * inv_sw_sum;  pdv.x = csv.x * (nom[0] * frcp(den[0] + kEPS));
        csv.y = den[1] * inv_sw_sum;  pdv.y = csv.y * (nom[1] * frcp(den[1] + kEPS));
        csv.z = den[2] * inv_sw_sum;  pdv.z = csv.z * (nom[2] * frcp(den[2] + kEPS));
        csv.w = den[3] * inv_sw_sum;  pdv.w = csv.w * (nom[3] * frcp(den[3] + kEPS));

        // Channel-mix partial accumulation (o statically unrolled).
        #pragma unroll
        for (int o = 0; o < NC; ++o) {
            const float wcv = lds_cw[o * NC + c];       // uniform -> broadcast
            an[o].x = fmaf(pdv.x, wcv, an[o].x);
            an[o].y = fmaf(pdv.y, wcv, an[o].y);
            an[o].z = fmaf(pdv.z, wcv, an[o].z);
            an[o].w = fmaf(pdv.w, wcv, an[o].w);
            ad[o].x = fmaf(csv.x, wcv, ad[o].x);
            ad[o].y = fmaf(csv.y, wcv, ad[o].y);
            ad[o].z = fmaf(csv.z, wcv, ad[o].z);
            ad[o].w = fmaf(csv.w, wcv, ad[o].w);
        }
    }

    // ---- Exchange: write partner's o-range partials to LDS (static idx) ----
    #define XWRITE(BASE)                                                   \
        _Pragma("unroll")                                                  \
        for (int ol = 0; ol < 8; ++ol) {                                   \
            *(float4*)&lds_x[wv][ol][0][w0] = an[(BASE) + ol];             \
            *(float4*)&lds_x[wv][ol][1][w0] = ad[(BASE) + ol];             \
        }
    if (wv == 0) { XWRITE(8) } else { XWRITE(0) }
    #undef XWRITE

    __syncthreads();

    // ---- Finalize own o-range: own partial + partner partial, epilogue ----
    // Outputs are never re-read -> non-temporal stores (keep L2 for d/cd).
    const size_t outb = (size_t)b * NC * HW + pix;
    #define FINISH(BASE)                                                   \
        _Pragma("unroll")                                                  \
        for (int ol = 0; ol < 8; ++ol) {                                   \
            const int o = (BASE) + ol;                                     \
            const float4 xn = *(const float4*)&lds_x[wv ^ 1][ol][0][w0];   \
            const float4 xd = *(const float4*)&lds_x[wv ^ 1][ol][1][w0];   \
            const float nx = an[o].x + xn.x, dx = ad[o].x + xd.x;          \
            const float ny = an[o].y + xn.y, dy = ad[o].y + xd.y;          \
            const float nz = an[o].z + xn.z, dz = ad[o].z + xd.z;          \
            const float nw_ = an[o].w + xn.w, dw = ad[o].w + xd.w;         \
            vf4 dv, cv;                                                    \
            dv[0] = nx * frcp(dx + kEPS);  cv[0] = dx * inv_cw_sum;        \
            dv[1] = ny * frcp(dy + kEPS);  cv[1] = dy * inv_cw_sum;        \
            dv[2] = nz * frcp(dz + kEPS);  cv[2] = dz * inv_cw_sum;        \
            dv[3] = nw_ * frcp(dw + kEPS); cv[3] = dw * inv_cw_sum;        \
            __builtin_nontemporal_store(dv, (vf4*)(g_dout  + outb + (size_t)o * HW)); \
            __builtin_nontemporal_store(cv, (vf4*)(g_cdout + outb + (size_t)o * HW)); \
        }
    if (wv == 0) { FINISH(0) } else { FINISH(8) }
    #undef FINISH
}

extern "C" void kernel_launch(void* const* d_in, const int* in_sizes, int n_in,
                              void* d_out, int out_size, void* d_ws, size_t ws_size,
                              hipStream_t stream) {
    const float* g_d  = (const float*)d_in[0];
    const float* g_cd = (const float*)d_in[1];
    // d_in[2] = s, d_in[3] = cs : unused by the reference computation.
    const float* g_sp = (const float*)d_in[4];
    const float* g_sw = (const float*)d_in[5];
    const float* g_cw = (const float*)d_in[6];

    float* g_dout  = (float*)d_out;
    float* g_cdout = g_dout + (size_t)NB * NC * HW;

    const int blocks = NB * NH;   // 1024 one-row blocks, 2 c-split waves each
    structnconv_fused<<<blocks, TPB, 0, stream>>>(g_d, g_cd, g_sp, g_sw, g_cw,
                                                  g_dout, g_cdout);
}

// Round 11
// 38.341 us; speedup vs baseline: 1.1740x; 1.1740x over previous
//
#include <hip/hip_runtime.h>

// StructNConv2D_d_with_s — fused spatial (3x3) + channel (16x16) normalized conv.
// d,cd: (4,16,256,256) f32; s_prod_roll: (4,16,9,256,256) f32;
// spatial_weight: (16,1,9,1,1); channel_weight: (16,16,1,1).
// Outputs concatenated: d_out then cd_out, each (4,16,256,256) f32.
//
// R11 = R6 (best, 38.0us) + one-iteration-deferred channel mix. R6 order:
// loads -> wait -> spatial FMA -> mix FMA; during the ~128-FMA mix nothing
// is in flight. Now: issue iter ci's 27 loads, run MIX(ci-1) (independent,
// uses carried pd/cs = 8 VGPR), then wait + spatial(ci). DRAM stays busy
// under the mix block. No sp double-buffer (R4's 72-VGPR/scratch trap);
// no nt hints (R10: -7us, harness fill flushes caches between replays
// anyway and nt loses L2 coalescing).

#define NB 4
#define NC 16
#define NH 256
#define NW 256
#define NK 9
#define HW (NH * NW)
#define TPB 128

static constexpr float kEPS = 1e-20f;

__device__ __forceinline__ float frcp(float x) { return __builtin_amdgcn_rcpf(x); }

__global__ __launch_bounds__(TPB) void structnconv_fused(
    const float* __restrict__ g_d,
    const float* __restrict__ g_cd,
    const float* __restrict__ g_sp,   // s_prod_roll
    const float* __restrict__ g_sw,   // spatial_weight (16*9)
    const float* __restrict__ g_cw,   // channel_weight (16*16)
    float* __restrict__ g_dout,
    float* __restrict__ g_cdout)
{
    __shared__ float lds_sw[NC * NK];        // 576 B
    __shared__ float lds_cw[NC * NC];        // 1 KB
    __shared__ float lds_part[4];
    __shared__ float lds_x[2][8][2][NW];     // [writer][o_loc][an/ad][px] 32 KB

    const int t  = threadIdx.x;
    const int wv = t >> 6;        // wave id: 0 -> c 0..7, 1 -> c 8..15
    const int ln = t & 63;

    // ---- Stage weights + global sums (128 threads, 1 barrier) ----
    float s1 = g_sw[t];                       // t < 128 < 144
    float s2 = g_cw[t] + g_cw[TPB + t];
    lds_sw[t] = s1;
    lds_cw[t] = g_cw[t];
    lds_cw[TPB + t] = g_cw[TPB + t];
    if (t < NC * NK - TPB) {                  // 16 tail elements of sw
        const float v = g_sw[TPB + t];
        lds_sw[TPB + t] = v;
        s1 += v;
    }
    #pragma unroll
    for (int off = 32; off > 0; off >>= 1) {
        s1 += __shfl_down(s1, off);
        s2 += __shfl_down(s2, off);
    }
    if (ln == 0) {
        lds_part[wv]     = s1;
        lds_part[2 + wv] = s2;
    }
    __syncthreads();
    const float inv_sw_sum = frcp(lds_part[0] + lds_part[1] + kEPS);
    const float inv_cw_sum = frcp(lds_part[2] + lds_part[3] + kEPS);

    // ---- Block -> one (b,h) row (bijective XCD swizzle); thread -> 4 px ----
    const int bid = (int)blockIdx.x;                 // 0..1023
    const int swz = (bid & 7) * 128 + (bid >> 3);    // XCD n -> contiguous band
    const int b = swz >> 8;
    const int h = swz & (NH - 1);
    const int w0 = ln << 2;
    const int pix = h * NW + w0;

    // ---- Phase 1: spatial conv for this wave's 8 channels; channel-mix
    //      partials for ALL 16 o-channels, mix deferred by one iteration ----
    float4 an[NC], ad[NC];
    #pragma unroll
    for (int o = 0; o < NC; ++o) {
        an[o] = make_float4(0.f, 0.f, 0.f, 0.f);
        ad[o] = make_float4(0.f, 0.f, 0.f, 0.f);
    }

    // MIX(CC): rank-1 update of all 16 output-channel partials from the
    // carried pd/cs of channel CC. Independent of any in-flight loads.
    float4 pdP, csP;
    #define MIX(CC) do {                                                   \
        const int _c = (CC);                                               \
        _Pragma("unroll")                                                  \
        for (int o = 0; o < NC; ++o) {                                     \
            const float wcv = lds_cw[o * NC + _c];   /* uniform */         \
            an[o].x = fmaf(pdP.x, wcv, an[o].x);                           \
            an[o].y = fmaf(pdP.y, wcv, an[o].y);                           \
            an[o].z = fmaf(pdP.z, wcv, an[o].z);                           \
            an[o].w = fmaf(pdP.w, wcv, an[o].w);                           \
            ad[o].x = fmaf(csP.x, wcv, ad[o].x);                           \
            ad[o].y = fmaf(csP.y, wcv, ad[o].y);                           \
            ad[o].z = fmaf(csP.z, wcv, ad[o].z);                           \
            ad[o].w = fmaf(csP.w, wcv, ad[o].w);                           \
        }                                                                  \
    } while (0)

    #pragma unroll 1
    for (int ci = 0; ci < 8; ++ci) {
        const int c = (wv << 3) + ci;     // wave-uniform
        const float* pdd = g_d  + (size_t)(b * NC + c) * HW + pix;
        const float* pcc = g_cd + (size_t)(b * NC + c) * HW + pix;
        const float* pss = g_sp + ((size_t)(b * NC + c) * NK) * HW + pix;

        // ---- Issue this iteration's loads (stencil rows + sp stream) ----
        float dr[3][6], cr[3][6];
        #pragma unroll
        for (int r = 0; r < 3; ++r) {
            const int hh = h + r - 1;
            const int roff = (r - 1) * NW;
            if ((unsigned)hh < (unsigned)NH) {
                const float4 md = *(const float4*)(pdd + roff);
                const float4 mc = *(const float4*)(pcc + roff);
                dr[r][1] = md.x; dr[r][2] = md.y; dr[r][3] = md.z; dr[r][4] = md.w;
                cr[r][1] = mc.x; cr[r][2] = mc.y; cr[r][3] = mc.z; cr[r][4] = mc.w;
                dr[r][0] = (w0 > 0)      ? pdd[roff - 1] : 0.f;
                cr[r][0] = (w0 > 0)      ? pcc[roff - 1] : 0.f;
                dr[r][5] = (w0 + 4 < NW) ? pdd[roff + 4] : 0.f;
                cr[r][5] = (w0 + 4 < NW) ? pcc[roff + 4] : 0.f;
            } else {
                #pragma unroll
                for (int j = 0; j < 6; ++j) { dr[r][j] = 0.f; cr[r][j] = 0.f; }
            }
        }
        float4 sp[NK];
        #pragma unroll
        for (int k = 0; k < NK; ++k)
            sp[k] = *(const float4*)(pss + (size_t)k * HW);

        // ---- Deferred mix of previous channel: runs while loads fly ----
        if (ci != 0) { MIX(c - 1); }

        // ---- Spatial FMA block for this channel ----
        float nom[4] = {0.f, 0.f, 0.f, 0.f};
        float den[4] = {0.f, 0.f, 0.f, 0.f};
        #pragma unroll
        for (int r = 0; r < 3; ++r) {
            #pragma unroll
            for (int dj = 0; dj < 3; ++dj) {
                const int k = r * 3 + dj;
                const float wck = lds_sw[c * NK + k];   // uniform -> broadcast
                const float sv[4] = {sp[k].x, sp[k].y, sp[k].z, sp[k].w};
                #pragma unroll
                for (int p = 0; p < 4; ++p) {
                    const float cdp = cr[r][dj + p] * sv[p];
                    nom[p] = fmaf(cdp * dr[r][dj + p], wck, nom[p]);
                    den[p] = fmaf(cdp, wck, den[p]);
                }
            }
        }

        csP.x = den[0] * inv_sw_sum;  pdP.x = csP.x * (nom[0] * frcp(den[0] + kEPS));
        csP.y = den[1] * inv_sw_sum;  pdP.y = csP.y * (nom[1] * frcp(den[1] + kEPS));
        csP.z = den[2] * inv_sw_sum;  pdP.z = csP.z * (nom[2] * frcp(den[2] + kEPS));
        csP.w = den[3] * inv_sw_sum;  pdP.w = csP.w * (nom[3] * frcp(den[3] + kEPS));
    }
    MIX((wv << 3) + 7);   // drain the pipeline
    #undef MIX

    // ---- Exchange: write partner's o-range partials to LDS (static idx) ----
    #define XWRITE(BASE)                                                   \
        _Pragma("unroll")                                                  \
        for (int ol = 0; ol < 8; ++ol) {                                   \
            *(float4*)&lds_x[wv][ol][0][w0] = an[(BASE) + ol];             \
            *(float4*)&lds_x[wv][ol][1][w0] = ad[(BASE) + ol];             \
        }
    if (wv == 0) { XWRITE(8) } else { XWRITE(0) }
    #undef XWRITE

    __syncthreads();

    // ---- Finalize own o-range: own partial + partner partial, epilogue ----
    const size_t outb = (size_t)b * NC * HW + pix;
    #define FINISH(BASE)                                                   \
        _Pragma("unroll")                                                  \
        for (int ol = 0; ol < 8; ++ol) {                                   \
            const int o = (BASE) + ol;                                     \
            const float4 xn = *(const float4*)&lds_x[wv ^ 1][ol][0][w0];   \
            const float4 xd = *(const float4*)&lds_x[wv ^ 1][ol][1][w0];   \
            const float nx = an[o].x + xn.x, dx = ad[o].x + xd.x;          \
            const float ny = an[o].y + xn.y, dy = ad[o].y + xd.y;          \
            const float nz = an[o].z + xn.z, dz = ad[o].z + xd.z;          \
            const float nw_ = an[o].w + xn.w, dw = ad[o].w + xd.w;         \
            float4 dv, cv;                                                 \
            dv.x = nx * frcp(dx + kEPS);  cv.x = dx * inv_cw_sum;          \
            dv.y = ny * frcp(dy + kEPS);  cv.y = dy * inv_cw_sum;          \
            dv.z = nz * frcp(dz + kEPS);  cv.z = dz * inv_cw_sum;          \
            dv.w = nw_ * frcp(dw + kEPS); cv.w = dw * inv_cw_sum;          \
            *(float4*)(g_dout  + outb + (size_t)o * HW) = dv;              \
            *(float4*)(g_cdout + outb + (size_t)o * HW) = cv;              \
        }
    if (wv == 0) { FINISH(0) } else { FINISH(8) }
    #undef FINISH
}

extern "C" void kernel_launch(void* const* d_in, const int* in_sizes, int n_in,
                              void* d_out, int out_size, void* d_ws, size_t ws_size,
                              hipStream_t stream) {
    const float* g_d  = (const float*)d_in[0];
    const float* g_cd = (const float*)d_in[1];
    // d_in[2] = s, d_in[3] = cs : unused by the reference computation.
    const float* g_sp = (const float*)d_in[4];
    const float* g_sw = (const float*)d_in[5];
    const float* g_cw = (const float*)d_in[6];

    float* g_dout  = (float*)d_out;
    float* g_cdout = g_dout + (size_t)NB * NC * HW;

    const int blocks = NB * NH;   // 1024 one-row blocks, 2 c-split waves each
    structnconv_fused<<<blocks, TPB, 0, stream>>>(g_d, g_cd, g_sp, g_sw, g_cw,
                                                  g_dout, g_cdout);
}

// Round 12
// 36.597 us; speedup vs baseline: 1.2299x; 1.0476x over previous
//
#include <hip/hip_runtime.h>

// StructNConv2D_d_with_s — fused spatial (3x3) + channel (16x16) normalized conv.
// d,cd: (4,16,256,256) f32; s_prod_roll: (4,16,9,256,256) f32;
// spatial_weight: (16,1,9,1,1); channel_weight: (16,16,1,1).
// Outputs concatenated: d_out then cd_out, each (4,16,256,256) f32.
//
// R12 = R6 (best, 38.0us) + shuffle-sourced stencil halo. The 12 scalar
// edge loads per c-iter (44% of VMEM instrs, 1.5% of bytes) are replaced by
// __shfl_up/down from the neighbor lane's float4 (lane ln's left pixel ==
// lane ln-1's md.w; right == lane ln+1's md.x). Row-boundary lanes (0/63)
// keep the existing zero-pad ternaries. VMEM instrs/c-iter: 27 -> 15.
// Structure unchanged: 2 c-split waves/block, an/ad[16]f4 reg accumulators,
// half-exchange via 32KB LDS, bijective XCD swizzle.

#define NB 4
#define NC 16
#define NH 256
#define NW 256
#define NK 9
#define HW (NH * NW)
#define TPB 128

static constexpr float kEPS = 1e-20f;

__device__ __forceinline__ float frcp(float x) { return __builtin_amdgcn_rcpf(x); }

__global__ __launch_bounds__(TPB) void structnconv_fused(
    const float* __restrict__ g_d,
    const float* __restrict__ g_cd,
    const float* __restrict__ g_sp,   // s_prod_roll
    const float* __restrict__ g_sw,   // spatial_weight (16*9)
    const float* __restrict__ g_cw,   // channel_weight (16*16)
    float* __restrict__ g_dout,
    float* __restrict__ g_cdout)
{
    __shared__ float lds_sw[NC * NK];        // 576 B
    __shared__ float lds_cw[NC * NC];        // 1 KB
    __shared__ float lds_part[4];
    __shared__ float lds_x[2][8][2][NW];     // [writer][o_loc][an/ad][px] 32 KB

    const int t  = threadIdx.x;
    const int wv = t >> 6;        // wave id: 0 -> c 0..7, 1 -> c 8..15
    const int ln = t & 63;

    // ---- Stage weights + global sums (128 threads, 1 barrier) ----
    float s1 = g_sw[t];                       // t < 128 < 144
    float s2 = g_cw[t] + g_cw[TPB + t];
    lds_sw[t] = s1;
    lds_cw[t] = g_cw[t];
    lds_cw[TPB + t] = g_cw[TPB + t];
    if (t < NC * NK - TPB) {                  // 16 tail elements of sw
        const float v = g_sw[TPB + t];
        lds_sw[TPB + t] = v;
        s1 += v;
    }
    #pragma unroll
    for (int off = 32; off > 0; off >>= 1) {
        s1 += __shfl_down(s1, off);
        s2 += __shfl_down(s2, off);
    }
    if (ln == 0) {
        lds_part[wv]     = s1;
        lds_part[2 + wv] = s2;
    }
    __syncthreads();
    const float inv_sw_sum = frcp(lds_part[0] + lds_part[1] + kEPS);
    const float inv_cw_sum = frcp(lds_part[2] + lds_part[3] + kEPS);

    // ---- Block -> one (b,h) row (bijective XCD swizzle); thread -> 4 px ----
    const int bid = (int)blockIdx.x;                 // 0..1023
    const int swz = (bid & 7) * 128 + (bid >> 3);    // XCD n -> contiguous band
    const int b = swz >> 8;
    const int h = swz & (NH - 1);
    const int w0 = ln << 2;
    const int pix = h * NW + w0;

    // ---- Phase 1: spatial conv for this wave's 8 channels; accumulate
    //      channel-mix partials for ALL 16 output channels in registers ----
    float4 an[NC], ad[NC];
    #pragma unroll
    for (int o = 0; o < NC; ++o) {
        an[o] = make_float4(0.f, 0.f, 0.f, 0.f);
        ad[o] = make_float4(0.f, 0.f, 0.f, 0.f);
    }

    #pragma unroll 1
    for (int ci = 0; ci < 8; ++ci) {
        const int c = (wv << 3) + ci;     // wave-uniform
        const float* pdd = g_d  + (size_t)(b * NC + c) * HW + pix;
        const float* pcc = g_cd + (size_t)(b * NC + c) * HW + pix;
        const float* pss = g_sp + ((size_t)(b * NC + c) * NK) * HW + pix;

        // Stencil rows -> registers; halo from neighbor lanes via shuffle.
        float dr[3][6], cr[3][6];
        #pragma unroll
        for (int r = 0; r < 3; ++r) {
            const int hh = h + r - 1;
            const int roff = (r - 1) * NW;
            if ((unsigned)hh < (unsigned)NH) {            // wave-uniform
                const float4 md = *(const float4*)(pdd + roff);
                const float4 mc = *(const float4*)(pcc + roff);
                dr[r][1] = md.x; dr[r][2] = md.y; dr[r][3] = md.z; dr[r][4] = md.w;
                cr[r][1] = mc.x; cr[r][2] = mc.y; cr[r][3] = mc.z; cr[r][4] = mc.w;
                // Halo: lane ln's left px = lane ln-1's md.w; right = ln+1's md.x.
                const float wl_d = __shfl_up(md.w, 1);
                const float wl_c = __shfl_up(mc.w, 1);
                const float wr_d = __shfl_down(md.x, 1);
                const float wr_c = __shfl_down(mc.x, 1);
                dr[r][0] = (w0 > 0)      ? wl_d : 0.f;    // lane 0 -> zero pad
                cr[r][0] = (w0 > 0)      ? wl_c : 0.f;
                dr[r][5] = (w0 + 4 < NW) ? wr_d : 0.f;    // lane 63 -> zero pad
                cr[r][5] = (w0 + 4 < NW) ? wr_c : 0.f;
            } else {
                #pragma unroll
                for (int j = 0; j < 6; ++j) { dr[r][j] = 0.f; cr[r][j] = 0.f; }
            }
        }

        float4 sp[NK];
        #pragma unroll
        for (int k = 0; k < NK; ++k)
            sp[k] = *(const float4*)(pss + (size_t)k * HW);

        float nom[4] = {0.f, 0.f, 0.f, 0.f};
        float den[4] = {0.f, 0.f, 0.f, 0.f};
        #pragma unroll
        for (int r = 0; r < 3; ++r) {
            #pragma unroll
            for (int dj = 0; dj < 3; ++dj) {
                const int k = r * 3 + dj;
                const float wck = lds_sw[c * NK + k];   // uniform -> broadcast
                const float sv[4] = {sp[k].x, sp[k].y, sp[k].z, sp[k].w};
                #pragma unroll
                for (int p = 0; p < 4; ++p) {
                    const float cdp = cr[r][dj + p] * sv[p];
                    nom[p] = fmaf(cdp * dr[r][dj + p], wck, nom[p]);
                    den[p] = fmaf(cdp, wck, den[p]);
                }
            }
        }

        float4 csv, pdv;
        csv.x = den[0] * inv_sw_sum;  pdv.x = csv.x * (nom[0] * frcp(den[0] + kEPS));
        csv.y = den[1] * inv_sw_sum;  pdv.y = csv.y * (nom[1] * frcp(den[1] + kEPS));
        csv.z = den[2] * inv_sw_sum;  pdv.z = csv.z * (nom[2] * frcp(den[2] + kEPS));
        csv.w = den[3] * inv_sw_sum;  pdv.w = csv.w * (nom[3] * frcp(den[3] + kEPS));

        // Channel-mix partial accumulation (o statically unrolled).
        #pragma unroll
        for (int o = 0; o < NC; ++o) {
            const float wcv = lds_cw[o * NC + c];       // uniform -> broadcast
            an[o].x = fmaf(pdv.x, wcv, an[o].x);
            an[o].y = fmaf(pdv.y, wcv, an[o].y);
            an[o].z = fmaf(pdv.z, wcv, an[o].z);
            an[o].w = fmaf(pdv.w, wcv, an[o].w);
            ad[o].x = fmaf(csv.x, wcv, ad[o].x);
            ad[o].y = fmaf(csv.y, wcv, ad[o].y);
            ad[o].z = fmaf(csv.z, wcv, ad[o].z);
            ad[o].w = fmaf(csv.w, wcv, ad[o].w);
        }
    }

    // ---- Exchange: write partner's o-range partials to LDS (static idx) ----
    #define XWRITE(BASE)                                                   \
        _Pragma("unroll")                                                  \
        for (int ol = 0; ol < 8; ++ol) {                                   \
            *(float4*)&lds_x[wv][ol][0][w0] = an[(BASE) + ol];             \
            *(float4*)&lds_x[wv][ol][1][w0] = ad[(BASE) + ol];             \
        }
    if (wv == 0) { XWRITE(8) } else { XWRITE(0) }
    #undef XWRITE

    __syncthreads();

    // ---- Finalize own o-range: own partial + partner partial, epilogue ----
    const size_t outb = (size_t)b * NC * HW + pix;
    #define FINISH(BASE)                                                   \
        _Pragma("unroll")                                                  \
        for (int ol = 0; ol < 8; ++ol) {                                   \
            const int o = (BASE) + ol;                                     \
            const float4 xn = *(const float4*)&lds_x[wv ^ 1][ol][0][w0];   \
            const float4 xd = *(const float4*)&lds_x[wv ^ 1][ol][1][w0];   \
            const float nx = an[o].x + xn.x, dx = ad[o].x + xd.x;          \
            const float ny = an[o].y + xn.y, dy = ad[o].y + xd.y;          \
            const float nz = an[o].z + xn.z, dz = ad[o].z + xd.z;          \
            const float nw_ = an[o].w + xn.w, dw = ad[o].w + xd.w;         \
            float4 dv, cv;                                                 \
            dv.x = nx * frcp(dx + kEPS);  cv.x = dx * inv_cw_sum;          \
            dv.y = ny * frcp(dy + kEPS);  cv.y = dy * inv_cw_sum;          \
            dv.z = nz * frcp(dz + kEPS);  cv.z = dz * inv_cw_sum;          \
            dv.w = nw_ * frcp(dw + kEPS); cv.w = dw * inv_cw_sum;          \
            *(float4*)(g_dout  + outb + (size_t)o * HW) = dv;              \
            *(float4*)(g_cdout + outb + (size_t)o * HW) = cv;              \
        }
    if (wv == 0) { FINISH(0) } else { FINISH(8) }
    #undef FINISH
}

extern "C" void kernel_launch(void* const* d_in, const int* in_sizes, int n_in,
                              void* d_out, int out_size, void* d_ws, size_t ws_size,
                              hipStream_t stream) {
    const float* g_d  = (const float*)d_in[0];
    const float* g_cd = (const float*)d_in[1];
    // d_in[2] = s, d_in[3] = cs : unused by the reference computation.
    const float* g_sp = (const float*)d_in[4];
    const float* g_sw = (const float*)d_in[5];
    const float* g_cw = (const float*)d_in[6];

    float* g_dout  = (float*)d_out;
    float* g_cdout = g_dout + (size_t)NB * NC * HW;

    const int blocks = NB * NH;   // 1024 one-row blocks, 2 c-split waves each
    structnconv_fused<<<blocks, TPB, 0, stream>>>(g_d, g_cd, g_sp, g_sw, g_cw,
                                                  g_dout, g_cdout);
}